// Round 12
// baseline (233.666 us; speedup 1.0000x reference)
//
#include <hip/hip_runtime.h>
#include <math.h>

#define CC 64
typedef _Float16 f16;
typedef _Float16 half8_t __attribute__((ext_vector_type(8)));
typedef float f32x4 __attribute__((ext_vector_type(4)));

__device__ __forceinline__ float silu_f(float v) {
    return v / (1.0f + __expf(-v));
}

// ---------------- K_pre: fused k_up + k_wt + k_hist (independent works) ------
// blocks [0, nb_up): x = nf @ Wup ; [nb_up, +168): weight transposes+pack ;
// rest: receiver histogram. All read only inputs (memset(cnt) precedes).
__global__ __launch_bounds__(256) void k_pre(
        const float* __restrict__ nf, const float* __restrict__ Wup,
        float* __restrict__ x, int N,
        const float* __restrict__ w1, const float* __restrict__ w2,
        const float* __restrict__ w3, const float* __restrict__ w4,
        const float* __restrict__ Wd,
        f16* __restrict__ wT1, f16* __restrict__ wT2,
        f16* __restrict__ wT3, f16* __restrict__ wT4,
        float* __restrict__ wpack,
        const int* __restrict__ rcv, int* __restrict__ cnt, int E) {
    int nb_up = (N * CC + 255) >> 8;
    int b = blockIdx.x;
    if (b < nb_up) {
        int tid = b * 256 + threadIdx.x;
        if (tid >= N * CC) return;
        int n = tid >> 6;
        int j = tid & 63;
        const float* nfr = nf + (size_t)n * CC;
        float acc = 0.f;
#pragma unroll
        for (int k = 0; k < CC; ++k) acc += nfr[k] * Wup[k * CC + j];
        x[tid] = acc;
    } else if (b < nb_up + 168) {
        int i = (b - nb_up) * 256 + threadIdx.x;
        if (i < 2048) {
            int n = i >> 5, k = i & 31;
            wT1[i] = (k < 8) ? (f16)w1[k * 64 + n] : (f16)0.f;
        } else if (i < 6144) {
            int j = i - 2048; int n = j >> 6, k = j & 63;
            wT2[j] = (f16)w2[k * 64 + n];
        } else if (i < 10240) {
            int j = i - 6144; int n = j >> 6, k = j & 63;
            wT3[j] = (f16)w3[k * 64 + n];
        } else if (i < 26624) {
            int j = i - 10240; int l = j >> 12; int r = j & 4095;
            int n = r >> 6, k = r & 63;
            wT4[j] = (f16)w4[k * 256 + l * 64 + n];
        } else if (i < 43008) {
            int j = i - 26624;          // element of wpack[4096][4]
            int pos = j >> 2;           // c*64 + d
            int comp = j & 3;           // l
            wpack[j] = 0.25f * Wd[comp * 4096 + pos];
        }
    } else {
        int e = (b - nb_up - 168) * 256 + threadIdx.x;
        if (e < E) atomicAdd(&cnt[rcv[e]], 1);
    }
}

// ---------------- CSR build: scan -> fill(+sph) ------------------------------
__global__ __launch_bounds__(1024) void k_scan(const int* __restrict__ cnt,
        int* __restrict__ off, int* __restrict__ cur, int N) {
    __shared__ int wsum[16];
    int t = threadIdx.x;
    int wave = t >> 6, lane = t & 63;
    int per = (N + 1023) >> 10;
    int i0 = t * per;
    int s = 0;
    for (int j = 0; j < per; ++j) {
        int i = i0 + j;
        if (i < N) s += cnt[i];
    }
    int sc = s;
#pragma unroll
    for (int d = 1; d < 64; d <<= 1) {
        int u = __shfl_up(sc, d, 64);
        if (lane >= d) sc += u;
    }
    if (lane == 63) wsum[wave] = sc;
    __syncthreads();
    if (wave == 0) {
        int v = (lane < 16) ? wsum[lane] : 0;
        int s2 = v;
#pragma unroll
        for (int d = 1; d < 16; d <<= 1) {
            int u = __shfl_up(s2, d, 64);
            if (lane >= d) s2 += u;
        }
        if (lane < 16) wsum[lane] = s2;
    }
    __syncthreads();
    int base = ((wave > 0) ? wsum[wave - 1] : 0) + (sc - s);
    int run = base;
    for (int j = 0; j < per; ++j) {
        int i = i0 + j;
        if (i < N) { off[i] = run; cur[i] = run; run += cnt[i]; }
    }
    if (t == 1023) off[N] = run;
}

// fill CSR slots + fused spherical harmonics (written directly in CSR order)
__global__ void k_fill(const int* __restrict__ rcv, const int* __restrict__ snd,
                       const float* __restrict__ vec, int* __restrict__ cur,
                       int* __restrict__ eid, int* __restrict__ sndp,
                       float* __restrict__ yb, int E) {
    int e = blockIdx.x * blockDim.x + threadIdx.x;
    if (e >= E) return;
    int p = atomicAdd(&cur[rcv[e]], 1);
    eid[p] = e;
    sndp[p] = snd[e];

    float vx = vec[(size_t)e * 3 + 0];
    float vy = vec[(size_t)e * 3 + 1];
    float vz = vec[(size_t)e * 3 + 2];
    float nrm = sqrtf(vx * vx + vy * vy + vz * vz) + 1e-12f;
    float rinv = 1.0f / nrm;
    float ux = vx * rinv, uy = vy * rinv, uz = vz * rinv;

    const float s3 = 1.7320508075688772f;
    const float s5 = 2.2360679774997896f;
    const float s15 = 3.8729833462074170f;
    const float c1 = 2.0916500663351889f;
    const float c2 = 10.246950765959598f;
    const float c3 = 1.6201851746019651f;
    const float c4 = 1.3228756555322954f;

    float zz = uz * uz, xx = ux * ux, yy = uy * uy;
    float4 r0 = {1.0f, s3 * ux, s3 * uy, s3 * uz};
    float4 r1 = {s15 * ux * uy, s15 * uy * uz, 0.5f * s5 * (3.f * zz - 1.f),
                 s15 * ux * uz};
    float4 r2 = {0.5f * s15 * (xx - yy), c1 * uy * (3.f * xx - yy),
                 c2 * ux * uy * uz, c3 * uy * (5.f * zz - 1.f)};
    float4 r3 = {c4 * uz * (5.f * zz - 3.f), c3 * ux * (5.f * zz - 1.f),
                 0.5f * c2 * uz * (xx - yy), c1 * ux * (xx - yy)};
    float* yr = yb + (size_t)p * 16;
    *(float4*)(yr + 0)  = r0;
    *(float4*)(yr + 4)  = r1;
    *(float4*)(yr + 8)  = r2;
    *(float4*)(yr + 12) = r3;
}

// ---------------- K1: radial MLP — nt-split waves, 32 rows/block -------------
// Round-10 analysis: k_mlp capped at E/32 = 5000 waves (4.9/SIMD max, 29%
// occupancy) because 32 rows/wave is needed for B-fragment amortization.
// Fix: keep 32 rows per BLOCK, but layers 1-3 split the OUTPUT-COLUMN (nt)
// dim across the block's 2 waves (wave w: nt = 2w, 2w+1; all 32 rows), so
// per-block B traffic is unchanged while waves double to 10000 (9.8/SIMD).
// Layer 4 switches to m-split (wave w owns rows [16w,16w+16), all nt) so the
// reshuffle+sf store is wave-private. 5 block barriers (2-wave, cheap).
__global__ __launch_bounds__(128) void k_mlp(const float* __restrict__ rad,
        const f16* __restrict__ wT1, const f16* __restrict__ wT2,
        const f16* __restrict__ wT3, const f16* __restrict__ wT4,
        const int* __restrict__ eid, const int* __restrict__ sndp,
        const float* __restrict__ x, f16* __restrict__ mixp, int E) {
    __shared__ f16 act[32][72];

    int t = threadIdx.x;
    int e0 = blockIdx.x * 32;
    int lane = t & 63;
    int wid = t >> 6;          // 0..1
    int fm = lane & 15;
    int q  = lane >> 4;
    int nt0 = wid * 2;         // this wave's first nt column-tile (layers 1-3)
    int mb  = wid * 16;        // this wave's m-tile base (layer 4)

    const half8_t hz = {0, 0, 0, 0, 0, 0, 0, 0};

    // ---- sf loads for the wave's own layer-4 rows (issued early) ----
    float4 sfa[2], sfb[2];
#pragma unroll
    for (int it = 0; it < 2; ++it) {
        int row = (lane >> 3) + it * 8;        // 0..15
        int ci = e0 + mb + row;
        int s = (ci < E) ? sndp[ci] : 0;
        const float* xr = x + (size_t)s * 64 + (lane & 7) * 8;
        sfa[it] = *(const float4*)xr;
        sfb[it] = *(const float4*)(xr + 4);
    }

    // ---- layer 1 via MFMA (k=8 zero-padded to K=32); both waves load both
    //      m-tiles' A-frags (rad gather duplicated across waves, ~5MB extra) --
    half8_t a0 = hz, a1 = hz;
    if (q == 0) {
        int ci0 = e0 + fm;
        if (ci0 < E) {
            int e = eid[ci0];
            float4 p0 = *(const float4*)(rad + (size_t)e * 8);
            float4 p1 = *(const float4*)(rad + (size_t)e * 8 + 4);
            a0 = (half8_t){(f16)p0.x, (f16)p0.y, (f16)p0.z, (f16)p0.w,
                           (f16)p1.x, (f16)p1.y, (f16)p1.z, (f16)p1.w};
        }
        int ci1 = e0 + 16 + fm;
        if (ci1 < E) {
            int e = eid[ci1];
            float4 p0 = *(const float4*)(rad + (size_t)e * 8);
            float4 p1 = *(const float4*)(rad + (size_t)e * 8 + 4);
            a1 = (half8_t){(f16)p0.x, (f16)p0.y, (f16)p0.z, (f16)p0.w,
                           (f16)p1.x, (f16)p1.y, (f16)p1.z, (f16)p1.w};
        }
    }
#pragma unroll
    for (int ntl = 0; ntl < 2; ++ntl) {
        int nt = nt0 + ntl;
        half8_t b = *(const half8_t*)(wT1 + ((nt * 16 + fm) << 5) + q * 8);
        f32x4 c0 = {0.f, 0.f, 0.f, 0.f};
        c0 = __builtin_amdgcn_mfma_f32_16x16x32_f16(a0, b, c0, 0, 0, 0);
        f32x4 c1 = {0.f, 0.f, 0.f, 0.f};
        c1 = __builtin_amdgcn_mfma_f32_16x16x32_f16(a1, b, c1, 0, 0, 0);
#pragma unroll
        for (int r = 0; r < 4; ++r) {
            act[q * 4 + r][nt * 16 + fm]      = (f16)silu_f(c0[r]);
            act[16 + q * 4 + r][nt * 16 + fm] = (f16)silu_f(c1[r]);
        }
    }
    __syncthreads();                               // B1: L1 writes -> L2 reads

    auto loadA = [&](int mbase, int kc) -> half8_t {
        return *(const half8_t*)&act[mbase + fm][kc + q * 8];
    };

    // ---- layers 2, 3: nt-split; A-frags cover both m-tiles, full K ----
    const f16* wts[2] = {wT2, wT3};
#pragma unroll
    for (int L = 0; L < 2; ++L) {
        const f16* wT = wts[L];
        half8_t a00 = loadA(0, 0),  a01 = loadA(0, 32);
        half8_t a10 = loadA(16, 0), a11 = loadA(16, 32);
        __syncthreads();                           // reads done -> writes safe
#pragma unroll
        for (int ntl = 0; ntl < 2; ++ntl) {
            int nt = nt0 + ntl;
            const f16* wr = wT + ((nt * 16 + fm) << 6);
            half8_t b0 = *(const half8_t*)(wr + q * 8);
            half8_t b1 = *(const half8_t*)(wr + 32 + q * 8);
            f32x4 c0 = {0.f, 0.f, 0.f, 0.f};
            c0 = __builtin_amdgcn_mfma_f32_16x16x32_f16(a00, b0, c0, 0, 0, 0);
            c0 = __builtin_amdgcn_mfma_f32_16x16x32_f16(a01, b1, c0, 0, 0, 0);
            f32x4 c1 = {0.f, 0.f, 0.f, 0.f};
            c1 = __builtin_amdgcn_mfma_f32_16x16x32_f16(a10, b0, c1, 0, 0, 0);
            c1 = __builtin_amdgcn_mfma_f32_16x16x32_f16(a11, b1, c1, 0, 0, 0);
#pragma unroll
            for (int r = 0; r < 4; ++r) {
                act[q * 4 + r][nt * 16 + fm]      = (f16)silu_f(c0[r]);
                act[16 + q * 4 + r][nt * 16 + fm] = (f16)silu_f(c1[r]);
            }
        }
        __syncthreads();                           // writes visible to next L
    }

    // ---- layer 4: m-split, wave-private rows [mb, mb+16), all nt ----
    half8_t A0 = loadA(mb, 0), A1 = loadA(mb, 32);

#pragma unroll
    for (int l = 0; l < 4; ++l) {
        const f16* wT = wT4 + (l << 12);
#pragma unroll
        for (int nt = 0; nt < 4; ++nt) {
            const f16* wr = wT + ((nt * 16 + fm) << 6);
            half8_t b0 = *(const half8_t*)(wr + q * 8);
            half8_t b1 = *(const half8_t*)(wr + 32 + q * 8);
            f32x4 c0 = {0.f, 0.f, 0.f, 0.f};
            c0 = __builtin_amdgcn_mfma_f32_16x16x32_f16(A0, b0, c0, 0, 0, 0);
            c0 = __builtin_amdgcn_mfma_f32_16x16x32_f16(A1, b1, c0, 0, 0, 0);
#pragma unroll
            for (int r = 0; r < 4; ++r)
                act[mb + q * 4 + r][nt * 16 + fm] = (f16)c0[r];
        }
        // reshuffle + sf-multiply -> coalesced half8 stores (wave-own rows)
#pragma unroll
        for (int it = 0; it < 2; ++it) {
            int row = (lane >> 3) + it * 8;
            int ci = e0 + mb + row;
            if (ci < E) {
                half8_t v = *(const half8_t*)&act[mb + row][(lane & 7) * 8];
                half8_t w;
                w[0] = (f16)((float)v[0] * sfa[it].x);
                w[1] = (f16)((float)v[1] * sfa[it].y);
                w[2] = (f16)((float)v[2] * sfa[it].z);
                w[3] = (f16)((float)v[3] * sfa[it].w);
                w[4] = (f16)((float)v[4] * sfb[it].x);
                w[5] = (f16)((float)v[5] * sfb[it].y);
                w[6] = (f16)((float)v[6] * sfb[it].z);
                w[7] = (f16)((float)v[7] * sfb[it].w);
                *(half8_t*)&mixp[(size_t)ci * 256 + l * 64 + (lane & 7) * 8] = w;
            }
        }
    }
}

// ---------------- K2: gather, 1 node/wave, pure CSR streams ------------------
// sfm (= sf*mix) comes precomputed from k_mlp; no x-gather, no sndp. Per edge:
// 4 f16 sfm loads + staged-yb LDS + 15 FMA; then the verified wpack epilogue.
__global__ __launch_bounds__(256) void k_gather(
        const f16* __restrict__ mixp, const float* __restrict__ yb,
        const int* __restrict__ off, const f32x4* __restrict__ wpack,
        float* __restrict__ out, int N) {
    __shared__ float sbuf[4][64 * 20];
    __shared__ float ybs[4][16][16];
    int wv = threadIdx.x >> 6;
    int lane = threadIdx.x & 63;
    int n = blockIdx.x * 4 + wv;
    if (n >= N) return;

    float o[16];
#pragma unroll
    for (int i = 0; i < 16; ++i) o[i] = 0.f;

    auto process = [&](int i, int j) {
        const float* yr = &ybs[wv][j][0];
        f32x4 A  = *(const f32x4*)(yr + 0);
        f32x4 B  = *(const f32x4*)(yr + 4);
        f32x4 Cv = *(const f32x4*)(yr + 8);
        f32x4 D  = *(const f32x4*)(yr + 12);
        const f16* mr = mixp + (size_t)i * 256;
        float t0 = (float)mr[lane];
        float t1 = (float)mr[64 + lane];
        float t2 = (float)mr[128 + lane];
        float t3 = (float)mr[192 + lane];
        o[0]  += t0;
        o[1]  += t1 * A.y;
        o[2]  += t1 * A.z;
        o[3]  += t1 * A.w;
        o[4]  += t2 * B.x;
        o[5]  += t2 * B.y;
        o[6]  += t2 * B.z;
        o[7]  += t2 * B.w;
        o[8]  += t2 * Cv.x;
        o[9]  += t3 * Cv.y;
        o[10] += t3 * Cv.z;
        o[11] += t3 * Cv.w;
        o[12] += t3 * D.x;
        o[13] += t3 * D.y;
        o[14] += t3 * D.z;
        o[15] += t3 * D.w;
    };

    int beg = off[n], end = off[n + 1];
    for (int cb = beg; cb < end; cb += 16) {
        int m = end - cb; if (m > 16) m = 16;
        // cooperative chunk stage: 16 edges x 16 floats of yb = 1 f32x4/lane
        if (lane < m * 4) {
            f32x4 v = *(const f32x4*)(yb + (size_t)cb * 16 + lane * 4);
            *(f32x4*)&ybs[wv][lane >> 2][(lane & 3) * 4] = v;
        }
        int j = 0;
        for (; j + 1 < m; j += 2) { process(cb + j, j); process(cb + j + 1, j + 1); }
        if (j < m) process(cb + j, j);
    }

    // wave-private transpose: lane's o[16] -> sw[lane*20 + m], b128 writes
    float* sw = sbuf[wv];
#pragma unroll
    for (int a = 0; a < 4; ++a) {
        f32x4 vq = {o[4 * a + 0], o[4 * a + 1], o[4 * a + 2], o[4 * a + 3]};
        *(f32x4*)&sw[lane * 20 + 4 * a] = vq;
    }

    // down-proj: per c, 4 b128 broadcasts + ONE packed-Wd dwordx4 + fma quads
    f32x4 dA = {0.f, 0.f, 0.f, 0.f}, dB = dA, dC = dA, dD = dA;
#pragma unroll 2
    for (int c = 0; c < 64; ++c) {
        f32x4 q0 = *(const f32x4*)&sw[c * 20 + 0];
        f32x4 q1 = *(const f32x4*)&sw[c * 20 + 4];
        f32x4 q2 = *(const f32x4*)&sw[c * 20 + 8];
        f32x4 q3 = *(const f32x4*)&sw[c * 20 + 12];
        f32x4 wp = wpack[c * 64 + lane];   // {0.25*w0, 0.25*w1, 0.25*w2, 0.25*w3}
        f32x4 wA = {wp.x, wp.y, wp.y, wp.y};
        f32x4 wC4 = {wp.z, wp.w, wp.w, wp.w};
        dA += q0 * wA;
        dB += q1 * wp.z;
        dC += q2 * wC4;
        dD += q3 * wp.w;
    }

    float* outr = out + (size_t)n * 1024;
    outr[lane] = dA[0];
#pragma unroll
    for (int m = 0; m < 3; ++m) outr[64 + lane * 3 + m] = dA[1 + m];
    outr[256 + lane * 5 + 0] = dB[0];
    outr[256 + lane * 5 + 1] = dB[1];
    outr[256 + lane * 5 + 2] = dB[2];
    outr[256 + lane * 5 + 3] = dB[3];
    outr[256 + lane * 5 + 4] = dC[0];
    outr[576 + lane * 7 + 0] = dC[1];
    outr[576 + lane * 7 + 1] = dC[2];
    outr[576 + lane * 7 + 2] = dC[3];
    outr[576 + lane * 7 + 3] = dD[0];
    outr[576 + lane * 7 + 4] = dD[1];
    outr[576 + lane * 7 + 5] = dD[2];
    outr[576 + lane * 7 + 6] = dD[3];
}

extern "C" void kernel_launch(void* const* d_in, const int* in_sizes, int n_in,
                              void* d_out, int out_size, void* d_ws, size_t ws_size,
                              hipStream_t stream) {
    const float* vectors    = (const float*)d_in[0];
    const float* node_feats = (const float*)d_in[1];
    const float* radial     = (const float*)d_in[2];
    const float* W_up       = (const float*)d_in[3];
    const float* w1         = (const float*)d_in[4];
    const float* w2         = (const float*)d_in[5];
    const float* w3         = (const float*)d_in[6];
    const float* w4         = (const float*)d_in[7];
    const float* Wd         = (const float*)d_in[8];
    const int*   snd        = (const int*)d_in[9];
    const int*   rcv        = (const int*)d_in[10];
    float* out = (float*)d_out;

    int E = in_sizes[9];
    int N = in_sizes[1] / CC;

    // ws: wT1[2048]h | wT2[4096]h | wT3[4096]h | wT4[16384]h | wpack[16384]f |
    //     x [N*64]f | yb [E*16]f | mixp [E*256]h | cnt [N] | off [N+1] |
    //     cur [N] | eid [E] | sndp [E]
    f16*   wT1   = (f16*)d_ws;
    f16*   wT2   = wT1 + 2048;
    f16*   wT3   = wT2 + 4096;
    f16*   wT4   = wT3 + 4096;
    float* wpack = (float*)(wT4 + 16384);
    float* x     = wpack + 16384;
    float* yb    = x + (size_t)N * 64;
    f16*   mixp  = (f16*)(yb + (size_t)E * 16);
    int*   cnt   = (int*)(mixp + (size_t)E * 256);
    int*   off   = cnt + N;
    int*   cur   = off + (N + 1);
    int*   eid   = cur + N;
    int*   sndp  = eid + E;

    hipMemsetAsync(cnt, 0, (size_t)N * sizeof(int), stream);

    int nb_up = (N * CC + 255) / 256;
    int nb_hist = (E + 255) / 256;
    k_pre<<<nb_up + 168 + nb_hist, 256, 0, stream>>>(
        node_feats, W_up, x, N, w1, w2, w3, w4, Wd,
        wT1, wT2, wT3, wT4, wpack, rcv, cnt, E);
    k_scan<<<1, 1024, 0, stream>>>(cnt, off, cur, N);
    k_fill<<<(E + 255) / 256, 256, 0, stream>>>(rcv, snd, vectors, cur, eid, sndp, yb, E);
    k_mlp<<<(E + 31) / 32, 128, 0, stream>>>(radial, wT1, wT2, wT3, wT4,
                                             eid, sndp, x, mixp, E);
    k_gather<<<(N + 3) / 4, 256, 0, stream>>>(mixp, yb, off,
                                              (const f32x4*)wpack, out, N);
}

// Round 13
// 217.067 us; speedup vs baseline: 1.0765x; 1.0765x over previous
//
#include <hip/hip_runtime.h>
#include <math.h>

#define CC 64
typedef _Float16 f16;
typedef _Float16 half8_t __attribute__((ext_vector_type(8)));
typedef float f32x4 __attribute__((ext_vector_type(4)));

// fast silu: v_rcp_f32 instead of IEEE div sequence (output is f16-rounded)
__device__ __forceinline__ float silu_f(float v) {
    return v * __builtin_amdgcn_rcpf(1.0f + __expf(-v));
}

// ---------------- K_pre: fused k_up + k_wt + k_hist (independent works) ------
__global__ __launch_bounds__(256) void k_pre(
        const float* __restrict__ nf, const float* __restrict__ Wup,
        float* __restrict__ x, int N,
        const float* __restrict__ w1, const float* __restrict__ w2,
        const float* __restrict__ w3, const float* __restrict__ w4,
        const float* __restrict__ Wd,
        f16* __restrict__ wT1, f16* __restrict__ wT2,
        f16* __restrict__ wT3, f16* __restrict__ wT4,
        float* __restrict__ wpack,
        const int* __restrict__ rcv, int* __restrict__ cnt, int E) {
    int nb_up = (N * CC + 255) >> 8;
    int b = blockIdx.x;
    if (b < nb_up) {
        int tid = b * 256 + threadIdx.x;
        if (tid >= N * CC) return;
        int n = tid >> 6;
        int j = tid & 63;
        const float* nfr = nf + (size_t)n * CC;
        float acc = 0.f;
#pragma unroll
        for (int k = 0; k < CC; ++k) acc += nfr[k] * Wup[k * CC + j];
        x[tid] = acc;
    } else if (b < nb_up + 168) {
        int i = (b - nb_up) * 256 + threadIdx.x;
        if (i < 2048) {
            int n = i >> 5, k = i & 31;
            wT1[i] = (k < 8) ? (f16)w1[k * 64 + n] : (f16)0.f;
        } else if (i < 6144) {
            int j = i - 2048; int n = j >> 6, k = j & 63;
            wT2[j] = (f16)w2[k * 64 + n];
        } else if (i < 10240) {
            int j = i - 6144; int n = j >> 6, k = j & 63;
            wT3[j] = (f16)w3[k * 64 + n];
        } else if (i < 26624) {
            int j = i - 10240; int l = j >> 12; int r = j & 4095;
            int n = r >> 6, k = r & 63;
            wT4[j] = (f16)w4[k * 256 + l * 64 + n];
        } else if (i < 43008) {
            int j = i - 26624;          // element of wpack[4096][4]
            int pos = j >> 2;           // c*64 + d
            int comp = j & 3;           // l
            wpack[j] = 0.25f * Wd[comp * 4096 + pos];
        }
    } else {
        int e = (b - nb_up - 168) * 256 + threadIdx.x;
        if (e < E) atomicAdd(&cnt[rcv[e]], 1);
    }
}

// ---------------- CSR build: scan -> fill(+sph) ------------------------------
__global__ __launch_bounds__(1024) void k_scan(const int* __restrict__ cnt,
        int* __restrict__ off, int* __restrict__ cur, int N) {
    __shared__ int wsum[16];
    int t = threadIdx.x;
    int wave = t >> 6, lane = t & 63;
    int per = (N + 1023) >> 10;
    int i0 = t * per;
    int s = 0;
    for (int j = 0; j < per; ++j) {
        int i = i0 + j;
        if (i < N) s += cnt[i];
    }
    int sc = s;
#pragma unroll
    for (int d = 1; d < 64; d <<= 1) {
        int u = __shfl_up(sc, d, 64);
        if (lane >= d) sc += u;
    }
    if (lane == 63) wsum[wave] = sc;
    __syncthreads();
    if (wave == 0) {
        int v = (lane < 16) ? wsum[lane] : 0;
        int s2 = v;
#pragma unroll
        for (int d = 1; d < 16; d <<= 1) {
            int u = __shfl_up(s2, d, 64);
            if (lane >= d) s2 += u;
        }
        if (lane < 16) wsum[lane] = s2;
    }
    __syncthreads();
    int base = ((wave > 0) ? wsum[wave - 1] : 0) + (sc - s);
    int run = base;
    for (int j = 0; j < per; ++j) {
        int i = i0 + j;
        if (i < N) { off[i] = run; cur[i] = run; run += cnt[i]; }
    }
    if (t == 1023) off[N] = run;
}

// fill CSR slots + fused spherical harmonics (written directly in CSR order)
__global__ void k_fill(const int* __restrict__ rcv, const int* __restrict__ snd,
                       const float* __restrict__ vec, int* __restrict__ cur,
                       int* __restrict__ eid, int* __restrict__ sndp,
                       float* __restrict__ yb, int E) {
    int e = blockIdx.x * blockDim.x + threadIdx.x;
    if (e >= E) return;
    int p = atomicAdd(&cur[rcv[e]], 1);
    eid[p] = e;
    sndp[p] = snd[e];

    float vx = vec[(size_t)e * 3 + 0];
    float vy = vec[(size_t)e * 3 + 1];
    float vz = vec[(size_t)e * 3 + 2];
    float nrm = sqrtf(vx * vx + vy * vy + vz * vz) + 1e-12f;
    float rinv = 1.0f / nrm;
    float ux = vx * rinv, uy = vy * rinv, uz = vz * rinv;

    const float s3 = 1.7320508075688772f;
    const float s5 = 2.2360679774997896f;
    const float s15 = 3.8729833462074170f;
    const float c1 = 2.0916500663351889f;
    const float c2 = 10.246950765959598f;
    const float c3 = 1.6201851746019651f;
    const float c4 = 1.3228756555322954f;

    float zz = uz * uz, xx = ux * ux, yy = uy * uy;
    float4 r0 = {1.0f, s3 * ux, s3 * uy, s3 * uz};
    float4 r1 = {s15 * ux * uy, s15 * uy * uz, 0.5f * s5 * (3.f * zz - 1.f),
                 s15 * ux * uz};
    float4 r2 = {0.5f * s15 * (xx - yy), c1 * uy * (3.f * xx - yy),
                 c2 * ux * uy * uz, c3 * uy * (5.f * zz - 1.f)};
    float4 r3 = {c4 * uz * (5.f * zz - 3.f), c3 * ux * (5.f * zz - 1.f),
                 0.5f * c2 * uz * (xx - yy), c1 * ux * (xx - yy)};
    float* yr = yb + (size_t)p * 16;
    *(float4*)(yr + 0)  = r0;
    *(float4*)(yr + 4)  = r1;
    *(float4*)(yr + 8)  = r2;
    *(float4*)(yr + 12) = r3;
}

// ---------------- K1: radial MLP — r10 geometry + VALU-lean inner ops --------
// Geometry = round-10 proven optimum: 32 rows/wave, 2-wave block, no barriers,
// grid (E+63)/64. Changes vs r10 (VALU-issue was the limiter: VALUBusy 40% at
// 29% occupancy): (1) silu uses v_rcp_f32 (saves ~6 ops/call × 96 calls);
// (2) sf-multiply at store uses v_pk_mul_f16 on pre-converted f16 sf (4 ops
// vs 24 per store quad).
__global__ __launch_bounds__(128) void k_mlp(const float* __restrict__ rad,
        const f16* __restrict__ wT1, const f16* __restrict__ wT2,
        const f16* __restrict__ wT3, const f16* __restrict__ wT4,
        const int* __restrict__ eid, const int* __restrict__ sndp,
        const float* __restrict__ x, f16* __restrict__ mixp, int E) {
    __shared__ f16 act[64][72];

    int t = threadIdx.x;
    int e0 = blockIdx.x * 64;
    int lane = t & 63;
    int wid = t >> 6;          // 0..1
    int m0 = wid * 32;
    int fm = lane & 15;
    int q  = lane >> 4;

    const half8_t hz = {0, 0, 0, 0, 0, 0, 0, 0};

    // ---- issue sf loads early (consumed at layer-4 store) ----
    float4 sfa[4], sfb[4];
#pragma unroll
    for (int it = 0; it < 4; ++it) {
        int row = (lane >> 3) + it * 8;
        int ci = e0 + m0 + row;
        int s = (ci < E) ? sndp[ci] : 0;
        const float* xr = x + (size_t)s * 64 + (lane & 7) * 8;
        sfa[it] = *(const float4*)xr;
        sfb[it] = *(const float4*)(xr + 4);
    }

    // ---- layer 1 via MFMA (k=8 zero-padded to K=32) ----
    half8_t a0 = hz, a1 = hz;
    if (q == 0) {
        int ci0 = e0 + m0 + fm;
        if (ci0 < E) {
            int e = eid[ci0];
            float4 p0 = *(const float4*)(rad + (size_t)e * 8);
            float4 p1 = *(const float4*)(rad + (size_t)e * 8 + 4);
            a0 = (half8_t){(f16)p0.x, (f16)p0.y, (f16)p0.z, (f16)p0.w,
                           (f16)p1.x, (f16)p1.y, (f16)p1.z, (f16)p1.w};
        }
        int ci1 = e0 + m0 + 16 + fm;
        if (ci1 < E) {
            int e = eid[ci1];
            float4 p0 = *(const float4*)(rad + (size_t)e * 8);
            float4 p1 = *(const float4*)(rad + (size_t)e * 8 + 4);
            a1 = (half8_t){(f16)p0.x, (f16)p0.y, (f16)p0.z, (f16)p0.w,
                           (f16)p1.x, (f16)p1.y, (f16)p1.z, (f16)p1.w};
        }
    }
#pragma unroll
    for (int nt = 0; nt < 4; ++nt) {
        half8_t b = *(const half8_t*)(wT1 + ((nt * 16 + fm) << 5) + q * 8);
        f32x4 c0 = {0.f, 0.f, 0.f, 0.f};
        c0 = __builtin_amdgcn_mfma_f32_16x16x32_f16(a0, b, c0, 0, 0, 0);
        f32x4 c1 = {0.f, 0.f, 0.f, 0.f};
        c1 = __builtin_amdgcn_mfma_f32_16x16x32_f16(a1, b, c1, 0, 0, 0);
#pragma unroll
        for (int r = 0; r < 4; ++r) {
            act[m0 + q * 4 + r][nt * 16 + fm]      = (f16)silu_f(c0[r]);
            act[m0 + 16 + q * 4 + r][nt * 16 + fm] = (f16)silu_f(c1[r]);
        }
    }

    auto loadA = [&](int mbase, int kc) -> half8_t {
        return *(const half8_t*)&act[mbase + fm][kc + q * 8];
    };

    // ---- layers 2, 3: B from global wT (L1-hot) ----
    const f16* wts[2] = {wT2, wT3};
#pragma unroll
    for (int L = 0; L < 2; ++L) {
        const f16* wT = wts[L];
        half8_t a00 = loadA(m0, 0),      a01 = loadA(m0, 32);
        half8_t a10 = loadA(m0 + 16, 0), a11 = loadA(m0 + 16, 32);
#pragma unroll
        for (int nt = 0; nt < 4; ++nt) {
            const f16* wr = wT + ((nt * 16 + fm) << 6);
            half8_t b0 = *(const half8_t*)(wr + q * 8);
            half8_t b1 = *(const half8_t*)(wr + 32 + q * 8);
            f32x4 c0 = {0.f, 0.f, 0.f, 0.f};
            c0 = __builtin_amdgcn_mfma_f32_16x16x32_f16(a00, b0, c0, 0, 0, 0);
            c0 = __builtin_amdgcn_mfma_f32_16x16x32_f16(a01, b1, c0, 0, 0, 0);
            f32x4 c1 = {0.f, 0.f, 0.f, 0.f};
            c1 = __builtin_amdgcn_mfma_f32_16x16x32_f16(a10, b0, c1, 0, 0, 0);
            c1 = __builtin_amdgcn_mfma_f32_16x16x32_f16(a11, b1, c1, 0, 0, 0);
#pragma unroll
            for (int r = 0; r < 4; ++r) {
                act[m0 + q * 4 + r][nt * 16 + fm]      = (f16)silu_f(c0[r]);
                act[m0 + 16 + q * 4 + r][nt * 16 + fm] = (f16)silu_f(c1[r]);
            }
        }
    }

    // ---- convert sf to f16 once (pk_mul operand) ----
    half8_t sfh[4];
#pragma unroll
    for (int it = 0; it < 4; ++it) {
        sfh[it] = (half8_t){(f16)sfa[it].x, (f16)sfa[it].y,
                            (f16)sfa[it].z, (f16)sfa[it].w,
                            (f16)sfb[it].x, (f16)sfb[it].y,
                            (f16)sfb[it].z, (f16)sfb[it].w};
    }

    // ---- layer 4: 4 output chunks (one per irrep l), sf applied at store ----
    half8_t A00 = loadA(m0, 0),      A01 = loadA(m0, 32);
    half8_t A10 = loadA(m0 + 16, 0), A11 = loadA(m0 + 16, 32);

#pragma unroll
    for (int l = 0; l < 4; ++l) {
        const f16* wT = wT4 + (l << 12);
#pragma unroll
        for (int nt = 0; nt < 4; ++nt) {
            const f16* wr = wT + ((nt * 16 + fm) << 6);
            half8_t b0 = *(const half8_t*)(wr + q * 8);
            half8_t b1 = *(const half8_t*)(wr + 32 + q * 8);
            f32x4 c0 = {0.f, 0.f, 0.f, 0.f};
            c0 = __builtin_amdgcn_mfma_f32_16x16x32_f16(A00, b0, c0, 0, 0, 0);
            c0 = __builtin_amdgcn_mfma_f32_16x16x32_f16(A01, b1, c0, 0, 0, 0);
            f32x4 c1 = {0.f, 0.f, 0.f, 0.f};
            c1 = __builtin_amdgcn_mfma_f32_16x16x32_f16(A10, b0, c1, 0, 0, 0);
            c1 = __builtin_amdgcn_mfma_f32_16x16x32_f16(A11, b1, c1, 0, 0, 0);
#pragma unroll
            for (int r = 0; r < 4; ++r) {
                act[m0 + q * 4 + r][nt * 16 + fm]      = (f16)c0[r];
                act[m0 + 16 + q * 4 + r][nt * 16 + fm] = (f16)c1[r];
            }
        }
        // reshuffle + packed f16 sf-multiply -> coalesced half8 stores
#pragma unroll
        for (int it = 0; it < 4; ++it) {
            int row = (lane >> 3) + it * 8;
            int ci = e0 + m0 + row;
            if (ci < E) {
                half8_t v = *(const half8_t*)&act[m0 + row][(lane & 7) * 8];
                half8_t w = v * sfh[it];          // 4x v_pk_mul_f16
                *(half8_t*)&mixp[(size_t)ci * 256 + l * 64 + (lane & 7) * 8] = w;
            }
        }
    }
}

// ---------------- K2: gather, 1 node/wave, pure CSR streams ------------------
__global__ __launch_bounds__(256) void k_gather(
        const f16* __restrict__ mixp, const float* __restrict__ yb,
        const int* __restrict__ off, const f32x4* __restrict__ wpack,
        float* __restrict__ out, int N) {
    __shared__ float sbuf[4][64 * 20];
    __shared__ float ybs[4][16][16];
    int wv = threadIdx.x >> 6;
    int lane = threadIdx.x & 63;
    int n = blockIdx.x * 4 + wv;
    if (n >= N) return;

    float o[16];
#pragma unroll
    for (int i = 0; i < 16; ++i) o[i] = 0.f;

    auto process = [&](int i, int j) {
        const float* yr = &ybs[wv][j][0];
        f32x4 A  = *(const f32x4*)(yr + 0);
        f32x4 B  = *(const f32x4*)(yr + 4);
        f32x4 Cv = *(const f32x4*)(yr + 8);
        f32x4 D  = *(const f32x4*)(yr + 12);
        const f16* mr = mixp + (size_t)i * 256;
        float t0 = (float)mr[lane];
        float t1 = (float)mr[64 + lane];
        float t2 = (float)mr[128 + lane];
        float t3 = (float)mr[192 + lane];
        o[0]  += t0;
        o[1]  += t1 * A.y;
        o[2]  += t1 * A.z;
        o[3]  += t1 * A.w;
        o[4]  += t2 * B.x;
        o[5]  += t2 * B.y;
        o[6]  += t2 * B.z;
        o[7]  += t2 * B.w;
        o[8]  += t2 * Cv.x;
        o[9]  += t3 * Cv.y;
        o[10] += t3 * Cv.z;
        o[11] += t3 * Cv.w;
        o[12] += t3 * D.x;
        o[13] += t3 * D.y;
        o[14] += t3 * D.z;
        o[15] += t3 * D.w;
    };

    int beg = off[n], end = off[n + 1];
    for (int cb = beg; cb < end; cb += 16) {
        int m = end - cb; if (m > 16) m = 16;
        // cooperative chunk stage: 16 edges x 16 floats of yb = 1 f32x4/lane
        if (lane < m * 4) {
            f32x4 v = *(const f32x4*)(yb + (size_t)cb * 16 + lane * 4);
            *(f32x4*)&ybs[wv][lane >> 2][(lane & 3) * 4] = v;
        }
        int j = 0;
        for (; j + 1 < m; j += 2) { process(cb + j, j); process(cb + j + 1, j + 1); }
        if (j < m) process(cb + j, j);
    }

    // wave-private transpose: lane's o[16] -> sw[lane*20 + m], b128 writes
    float* sw = sbuf[wv];
#pragma unroll
    for (int a = 0; a < 4; ++a) {
        f32x4 vq = {o[4 * a + 0], o[4 * a + 1], o[4 * a + 2], o[4 * a + 3]};
        *(f32x4*)&sw[lane * 20 + 4 * a] = vq;
    }

    // down-proj: per c, 4 b128 broadcasts + ONE packed-Wd dwordx4 + fma quads
    f32x4 dA = {0.f, 0.f, 0.f, 0.f}, dB = dA, dC = dA, dD = dA;
#pragma unroll 2
    for (int c = 0; c < 64; ++c) {
        f32x4 q0 = *(const f32x4*)&sw[c * 20 + 0];
        f32x4 q1 = *(const f32x4*)&sw[c * 20 + 4];
        f32x4 q2 = *(const f32x4*)&sw[c * 20 + 8];
        f32x4 q3 = *(const f32x4*)&sw[c * 20 + 12];
        f32x4 wp = wpack[c * 64 + lane];   // {0.25*w0, 0.25*w1, 0.25*w2, 0.25*w3}
        f32x4 wA = {wp.x, wp.y, wp.y, wp.y};
        f32x4 wC4 = {wp.z, wp.w, wp.w, wp.w};
        dA += q0 * wA;
        dB += q1 * wp.z;
        dC += q2 * wC4;
        dD += q3 * wp.w;
    }

    float* outr = out + (size_t)n * 1024;
    outr[lane] = dA[0];
#pragma unroll
    for (int m = 0; m < 3; ++m) outr[64 + lane * 3 + m] = dA[1 + m];
    outr[256 + lane * 5 + 0] = dB[0];
    outr[256 + lane * 5 + 1] = dB[1];
    outr[256 + lane * 5 + 2] = dB[2];
    outr[256 + lane * 5 + 3] = dB[3];
    outr[256 + lane * 5 + 4] = dC[0];
    outr[576 + lane * 7 + 0] = dC[1];
    outr[576 + lane * 7 + 1] = dC[2];
    outr[576 + lane * 7 + 2] = dC[3];
    outr[576 + lane * 7 + 3] = dD[0];
    outr[576 + lane * 7 + 4] = dD[1];
    outr[576 + lane * 7 + 5] = dD[2];
    outr[576 + lane * 7 + 6] = dD[3];
}

extern "C" void kernel_launch(void* const* d_in, const int* in_sizes, int n_in,
                              void* d_out, int out_size, void* d_ws, size_t ws_size,
                              hipStream_t stream) {
    const float* vectors    = (const float*)d_in[0];
    const float* node_feats = (const float*)d_in[1];
    const float* radial     = (const float*)d_in[2];
    const float* W_up       = (const float*)d_in[3];
    const float* w1         = (const float*)d_in[4];
    const float* w2         = (const float*)d_in[5];
    const float* w3         = (const float*)d_in[6];
    const float* w4         = (const float*)d_in[7];
    const float* Wd         = (const float*)d_in[8];
    const int*   snd        = (const int*)d_in[9];
    const int*   rcv        = (const int*)d_in[10];
    float* out = (float*)d_out;

    int E = in_sizes[9];
    int N = in_sizes[1] / CC;

    // ws: wT1[2048]h | wT2[4096]h | wT3[4096]h | wT4[16384]h | wpack[16384]f |
    //     x [N*64]f | yb [E*16]f | mixp [E*256]h | cnt [N] | off [N+1] |
    //     cur [N] | eid [E] | sndp [E]
    f16*   wT1   = (f16*)d_ws;
    f16*   wT2   = wT1 + 2048;
    f16*   wT3   = wT2 + 4096;
    f16*   wT4   = wT3 + 4096;
    float* wpack = (float*)(wT4 + 16384);
    float* x     = wpack + 16384;
    float* yb    = x + (size_t)N * 64;
    f16*   mixp  = (f16*)(yb + (size_t)E * 16);
    int*   cnt   = (int*)(mixp + (size_t)E * 256);
    int*   off   = cnt + N;
    int*   cur   = off + (N + 1);
    int*   eid   = cur + N;
    int*   sndp  = eid + E;

    hipMemsetAsync(cnt, 0, (size_t)N * sizeof(int), stream);

    int nb_up = (N * CC + 255) / 256;
    int nb_hist = (E + 255) / 256;
    k_pre<<<nb_up + 168 + nb_hist, 256, 0, stream>>>(
        node_feats, W_up, x, N, w1, w2, w3, w4, Wd,
        wT1, wT2, wT3, wT4, wpack, rcv, cnt, E);
    k_scan<<<1, 1024, 0, stream>>>(cnt, off, cur, N);
    k_fill<<<(E + 255) / 256, 256, 0, stream>>>(rcv, snd, vectors, cur, eid, sndp, yb, E);
    k_mlp<<<(E + 63) / 64, 128, 0, stream>>>(radial, wT1, wT2, wT3, wT4,
                                             eid, sndp, x, mixp, E);
    k_gather<<<(N + 3) / 4, 256, 0, stream>>>(mixp, yb, off,
                                              (const f32x4*)wpack, out, N);
}